// Round 1
// baseline (685.301 us; speedup 1.0000x reference)
//
#include <hip/hip_runtime.h>

// Problem constants
#define N_NODES 20000
#define N_ATTRS 5000
#define IN_F    512
#define OUT_F   128
#define NK      160           // ksteps of 32 attrs (5120 padded)
#define WH2_PAD 5376          // wh2 allocation incl. pad
#define NEGBIG  -1e30f        // wh2 pad: exp2 underflows to 0 -> self-masking tail
#define LOG2E   1.4426950408889634f

typedef _Float16 f16x8 __attribute__((ext_vector_type(8)));
typedef float    f32x4 __attribute__((ext_vector_type(4)));
typedef int      i32x4 __attribute__((ext_vector_type(4)));

__device__ __forceinline__ float fast_exp2(float x) {
    return __builtin_amdgcn_exp2f(x);
}

// ---------------------------------------------------------------------------
// Kernel 1: Wa1 = W @ a[:128], Wa2 = W @ a[128:], pre-scaled by log2(e);
// repack W into f16 MFMA B-fragment order.
// ---------------------------------------------------------------------------
__global__ __launch_bounds__(256) void prep_kernel(
    const float* __restrict__ W, const float* __restrict__ a,
    float* __restrict__ Wa1, float* __restrict__ Wa2, _Float16* __restrict__ Wp) {
    int gt = blockIdx.x * blockDim.x + threadIdx.x;
    if (gt < IN_F) {
        int k = gt;
        float s1 = 0.f, s2 = 0.f;
        for (int f = 0; f < OUT_F; ++f) {
            float w = W[k * OUT_F + f];
            s1 += w * a[f];
            s2 += w * a[OUT_F + f];
        }
        Wa1[k] = s1 * LOG2E;
        Wa2[k] = s2 * LOG2E;
    }
    for (int idx = gt; idx < IN_F * OUT_F; idx += gridDim.x * blockDim.x) {
        int j    = idx & 7;
        int lane = (idx >> 3) & 63;
        int nb   = (idx >> 9) & 7;
        int kb   = idx >> 12;
        int k = kb * 32 + (lane >> 4) * 8 + j;
        int n = nb * 16 + (lane & 15);
        Wp[idx] = (_Float16)W[k * OUT_F + n];
    }
}

// ---------------------------------------------------------------------------
// Kernel 2: wh1[i] = node_emb[i] . Wa1 ; wh2[j] = attr_emb[j] . Wa2
// ---------------------------------------------------------------------------
__global__ __launch_bounds__(256) void wh_kernel(
    const float* __restrict__ node_emb, const float* __restrict__ attr_emb,
    const float* __restrict__ Wa1, const float* __restrict__ Wa2,
    float* __restrict__ wh1, float* __restrict__ wh2) {
    int wave = threadIdx.x >> 6, lane = threadIdx.x & 63;
    int r = blockIdx.x * 4 + wave;   // grid = 6250 -> r in [0, 25000)
    const float* src;
    const float* vec;
    float* dst;
    if (r < N_NODES) {
        src = node_emb + (size_t)r * IN_F; vec = Wa1; dst = wh1 + r;
    } else {
        int r2 = r - N_NODES;
        src = attr_emb + (size_t)r2 * IN_F; vec = Wa2; dst = wh2 + r2;
    }
    float4 ra = *reinterpret_cast<const float4*>(src + lane * 8);
    float4 rb = *reinterpret_cast<const float4*>(src + lane * 8 + 4);
    const float* vp = vec + lane * 8;
    float s = ra.x * vp[0] + ra.y * vp[1] + ra.z * vp[2] + ra.w * vp[3]
            + rb.x * vp[4] + rb.y * vp[5] + rb.z * vp[6] + rb.w * vp[7];
#pragma unroll
    for (int off = 1; off < 64; off <<= 1) s += __shfl_xor(s, off, 64);
    if (lane == 0) *dst = s;
}

// ---------------------------------------------------------------------------
// Kernel 2b: maxwh2 = max_j wh2[j]; fill wh2 pad with NEGBIG. single block.
// ---------------------------------------------------------------------------
__global__ __launch_bounds__(256) void max_kernel(
    float* __restrict__ wh2, float* __restrict__ maxp) {
    __shared__ float red[4];
    int t = threadIdx.x;
    float m = -1e30f;
    for (int j = t; j < N_ATTRS; j += 256) m = fmaxf(m, wh2[j]);
    for (int j = N_ATTRS + t; j < WH2_PAD; j += 256) wh2[j] = NEGBIG;
#pragma unroll
    for (int off = 1; off < 64; off <<= 1) m = fmaxf(m, __shfl_xor(m, off, 64));
    int wave = t >> 6, lane = t & 63;
    if (lane == 0) red[wave] = m;
    __syncthreads();
    if (t == 0) *maxp = fmaxf(fmaxf(red[0], red[1]), fmaxf(red[2], red[3]));
}

// ---------------------------------------------------------------------------
// Kernel 3: V = attr_emb @ W  [5120(pad) x 128] f16 in B-fragment order:
// Vp[kk*4096 + nb*512 + lane*8 + jj] = V[kk*32 + (lane>>4)*8 + jj][nb*16 + (lane&15)]
// ---------------------------------------------------------------------------
__global__ __launch_bounds__(256) void attr_h_kernel(
    const float* __restrict__ attr_emb, const _Float16* __restrict__ Wp,
    _Float16* __restrict__ Vp) {
    int wave = threadIdx.x >> 6, lane = threadIdx.x & 63;
    int m = lane & 15, quad = lane >> 4;
    int j0 = (blockIdx.x * 4 + wave) * 16;  // grid = 80 -> j0 in [0, 5120)
    int j = j0 + m;
    bool valid = j < N_ATTRS;
    f32x4 acc[8];
#pragma unroll
    for (int nb = 0; nb < 8; ++nb)
#pragma unroll
        for (int t = 0; t < 4; ++t) acc[nb][t] = 0.f;
    const float* arow = attr_emb + (size_t)j * IN_F;
    for (int kk = 0; kk < IN_F / 32; ++kk) {
        f16x8 afrag;
        if (valid) {
            float4 ra = *reinterpret_cast<const float4*>(arow + kk * 32 + quad * 8);
            float4 rb = *reinterpret_cast<const float4*>(arow + kk * 32 + quad * 8 + 4);
            afrag[0] = (_Float16)ra.x; afrag[1] = (_Float16)ra.y;
            afrag[2] = (_Float16)ra.z; afrag[3] = (_Float16)ra.w;
            afrag[4] = (_Float16)rb.x; afrag[5] = (_Float16)rb.y;
            afrag[6] = (_Float16)rb.z; afrag[7] = (_Float16)rb.w;
        } else {
#pragma unroll
            for (int t = 0; t < 8; ++t) afrag[t] = (_Float16)0.f;
        }
        const _Float16* wbase = Wp + (size_t)(kk * 8) * 64 * 8;
#pragma unroll
        for (int nb = 0; nb < 8; ++nb) {
            f16x8 bfrag;
            __builtin_memcpy(&bfrag, wbase + (nb * 64 + lane) * 8, 16);
            acc[nb] = __builtin_amdgcn_mfma_f32_16x16x32_f16(afrag, bfrag, acc[nb], 0, 0, 0);
        }
    }
#pragma unroll
    for (int nb = 0; nb < 8; ++nb) {
#pragma unroll
        for (int reg = 0; reg < 4; ++reg) {
            int jr = j0 + quad * 4 + reg;
            int n = nb * 16 + m;
            float v = (jr < N_ATTRS) ? acc[nb][reg] : 0.f;  // zero the K padding
            size_t idx = ((size_t)((jr >> 5) * 8 + nb) * 64 +
                          (((jr >> 3) & 3) * 16 + m)) * 8 + (jr & 7);
            Vp[idx] = (_Float16)v;
        }
    }
}

// ---------------------------------------------------------------------------
// Kernel 4 (main), barrier-free register-pipelined rewrite:
//  - 1 wave owns 16 complete rows, all 160 ksteps. grid 625 x 128 threads
//    (2 waves/block) = 1250 waves, all co-resident. No LDS, no syncthreads.
//  - feat (HBM, 400 MB, the only big stream): per-lane 32 B/kstep, register
//    ring of depth 8 (prefetch distance 8, fully unrolled -> static indices).
//    Per-wave in-flight cap 4 KB -> ~5 MB chip-wide > Little's-law 2.4 MB
//    needed to saturate 6.3 TB/s at ~900 cy latency.
//  - Vp B-fragments + wh2 (L2-resident): distance-1 double-buffered register
//    prefetch, issued BEFORE the feat prefetch each sub-iter so the in-order
//    vmcnt retire never forces a just-issued HBM load on the MFMA's wait.
// ---------------------------------------------------------------------------
__global__ __launch_bounds__(128) void attn_kernel(
    const int* __restrict__ feat, const float* __restrict__ wh1,
    const float* __restrict__ wh2, const float* __restrict__ maxwh2,
    const _Float16* __restrict__ Vp, float* __restrict__ out) {
    int wave = threadIdx.x >> 6, lane = threadIdx.x & 63;
    int m = lane & 15, quad = lane >> 4;
    int i0 = blockIdx.x * 32 + wave * 16;      // 625*32 = 20000 exact
    int row = i0 + m;

    float wh1i = wh1[row];                     // scaled by log2(e)
    float emax = wh1i + maxwh2[0];
    float Mi = fmaxf(emax, 0.2f * emax) - 12.f;   // f16 P in (0, 4096]

    f32x4 acc[8];
#pragma unroll
    for (int nb = 0; nb < 8; ++nb)
#pragma unroll
        for (int t = 0; t < 4; ++t) acc[nb][t] = 0.f;
    float s = 0.f;

    const int* fr = feat + (size_t)row * N_ATTRS;

    // feat register ring, depth 8 ksteps (32 attrs each)
    i32x4 rA[8], rB[8];
#pragma unroll
    for (int u = 0; u < 8; ++u) {
        int a = u * 32 + quad * 8;             // max 248, in-bounds
        rA[u] = *reinterpret_cast<const i32x4*>(fr + a);
        rB[u] = *reinterpret_cast<const i32x4*>(fr + a + 4);
    }

    // Vp/wh2 double buffer, prefetch distance 1
    f16x8  bf[2][8];
    float4 wva[2], wvb[2];
    {
        const _Float16* vb = Vp + (size_t)lane * 8;
#pragma unroll
        for (int nb = 0; nb < 8; ++nb)
            bf[0][nb] = *reinterpret_cast<const f16x8*>(vb + nb * 512);
        wva[0] = *reinterpret_cast<const float4*>(wh2 + quad * 8);
        wvb[0] = *reinterpret_cast<const float4*>(wh2 + quad * 8 + 4);
    }

    for (int kb = 0; kb < NK; kb += 8) {
#pragma unroll
        for (int u = 0; u < 8; ++u) {
            int k = kb + u;
            int cur = u & 1, nxt = cur ^ 1;
            // (a) prefetch Vp/wh2 for k+1 (L2) -- issued first on purpose
            int kn = (k + 1 < NK) ? (k + 1) : (NK - 1);
            const _Float16* vbn = Vp + (size_t)kn * 4096 + lane * 8;
#pragma unroll
            for (int nb = 0; nb < 8; ++nb)
                bf[nxt][nb] = *reinterpret_cast<const f16x8*>(vbn + nb * 512);
            wva[nxt] = *reinterpret_cast<const float4*>(wh2 + kn * 32 + quad * 8);
            wvb[nxt] = *reinterpret_cast<const float4*>(wh2 + kn * 32 + quad * 8 + 4);
            // (b) rotate feat ring: copy current, prefetch k+8 (HBM)
            i32x4 fa = rA[u], fb = rB[u];
            int an = (k + 8) * 32 + quad * 8;
            if (an > N_ATTRS - 8) an = N_ATTRS - 8;   // tail clamp; wh2 pad masks
            rA[u] = *reinterpret_cast<const i32x4*>(fr + an);
            rB[u] = *reinterpret_cast<const i32x4*>(fr + an + 4);
            // (c) compute kstep k
            int   fi[8] = {fa.x, fa.y, fa.z, fa.w, fb.x, fb.y, fb.z, fb.w};
            float wv[8] = {wva[cur].x, wva[cur].y, wva[cur].z, wva[cur].w,
                           wvb[cur].x, wvb[cur].y, wvb[cur].z, wvb[cur].w};
            f16x8 afrag;
#pragma unroll
            for (int t = 0; t < 8; ++t) {
                float e = wh1i + wv[t];            // pad attrs: e ~ -1e30
                float l = fmaxf(e, 0.2f * e);
                float p = fast_exp2(l - Mi);       // pad: exp2(-huge) = 0
                p = (fi[t] > 0) ? p : 0.f;
                _Float16 ph = (_Float16)p;
                s += (float)ph;                    // sum quantized p
                afrag[t] = ph;
            }
#pragma unroll
            for (int nb = 0; nb < 8; ++nb)
                acc[nb] = __builtin_amdgcn_mfma_f32_16x16x32_f16(
                    afrag, bf[cur][nb], acc[nb], 0, 0, 0);
        }
    }

    // row sums: combine the 4 quads (all attr blocks of each row)
    s += __shfl_xor(s, 16, 64);
    s += __shfl_xor(s, 32, 64);

    // normalize, ELU, store. acc[nb][reg] = h_prime[i0 + quad*4+reg][nb*16+m]
#pragma unroll
    for (int reg = 0; reg < 4; ++reg) {
        float rs = __shfl(s, quad * 4 + reg, 64);
        rs = (rs > 0.f) ? rs : 1.f;
        size_t ro = (size_t)(i0 + quad * 4 + reg) * OUT_F + m;
#pragma unroll
        for (int nb = 0; nb < 8; ++nb) {
            float h = acc[nb][reg] / rs;
            float ov = (h > 0.f) ? h : (fast_exp2(h * LOG2E) - 1.f);
            out[ro + nb * 16] = ov;
        }
    }
}

// ---------------------------------------------------------------------------
extern "C" void kernel_launch(void* const* d_in, const int* in_sizes, int n_in,
                              void* d_out, int out_size, void* d_ws, size_t ws_size,
                              hipStream_t stream) {
    const float* node_emb = (const float*)d_in[0];  // fp32 [20000,512]
    const float* attr_emb = (const float*)d_in[1];  // fp32 [5000,512]
    const int*   feat     = (const int*)d_in[2];    // int32 [20000,5000]
    const float* W        = (const float*)d_in[3];  // fp32 [512,128]
    const float* a        = (const float*)d_in[4];  // fp32 [256,1]
    float*       out      = (float*)d_out;          // fp32 [20000,128]

    char* ws = (char*)d_ws;
    float*    Wa1 = (float*)(ws + 0);          // 512 f32
    float*    Wa2 = (float*)(ws + 4096);       // 512 f32
    float*    wh1 = (float*)(ws + 8192);       // 20000 f32 (ends 88192)
    float*    wh2 = (float*)(ws + 90112);      // 5376 f32 incl. NEGBIG pad (ends 111616)
    float*    mx  = (float*)(ws + 111616);     // 1 f32
    _Float16* Wp  = (_Float16*)(ws + 131072);  // 65536 f16 (ends 262144)
    _Float16* Vp  = (_Float16*)(ws + 262144);  // 5120*128 f16 (ends 1572864)

    prep_kernel<<<64, 256, 0, stream>>>(W, a, Wa1, Wa2, Wp);
    wh_kernel<<<6250, 256, 0, stream>>>(node_emb, attr_emb, Wa1, Wa2, wh1, wh2);
    max_kernel<<<1, 256, 0, stream>>>(wh2, mx);
    attr_h_kernel<<<80, 256, 0, stream>>>(attr_emb, Wp, Vp);
    attn_kernel<<<625, 128, 0, stream>>>(feat, wh1, wh2, mx, Vp, out);
}

// Round 2
// 661.593 us; speedup vs baseline: 1.0358x; 1.0358x over previous
//
#include <hip/hip_runtime.h>

// Problem constants
#define N_NODES 20000
#define N_ATTRS 5000
#define IN_F    512
#define OUT_F   128
#define NK      160           // ksteps of 32 attrs (5120 padded)
#define NSS     80            // supersteps (2 ksteps each)
#define WH2_PAD 5376          // wh2 allocation incl. pad
#define NEGBIG  -1e30f        // wh2 pad: exp2 underflows to 0 -> self-masking tail
#define LOG2E   1.4426950408889634f

typedef _Float16 f16x8 __attribute__((ext_vector_type(8)));
typedef float    f32x4 __attribute__((ext_vector_type(4)));
typedef int      i32x4 __attribute__((ext_vector_type(4)));

__device__ __forceinline__ float fast_exp2(float x) {
    return __builtin_amdgcn_exp2f(x);
}

// async global->LDS DMA, 16 B per lane. LDS dest = wave-uniform base + lane*16.
__device__ __forceinline__ void async16(void* lds_dst, const void* gsrc) {
    __builtin_amdgcn_global_load_lds(
        (const __attribute__((address_space(1))) unsigned int*)gsrc,
        (__attribute__((address_space(3))) unsigned int*)lds_dst, 16, 0, 0);
}

// ---------------------------------------------------------------------------
// Kernel 1: Wa1 = W @ a[:128], Wa2 = W @ a[128:], pre-scaled by log2(e);
// repack W into f16 MFMA B-fragment order.
// ---------------------------------------------------------------------------
__global__ __launch_bounds__(256) void prep_kernel(
    const float* __restrict__ W, const float* __restrict__ a,
    float* __restrict__ Wa1, float* __restrict__ Wa2, _Float16* __restrict__ Wp) {
    int gt = blockIdx.x * blockDim.x + threadIdx.x;
    if (gt < IN_F) {
        int k = gt;
        float s1 = 0.f, s2 = 0.f;
        for (int f = 0; f < OUT_F; ++f) {
            float w = W[k * OUT_F + f];
            s1 += w * a[f];
            s2 += w * a[OUT_F + f];
        }
        Wa1[k] = s1 * LOG2E;
        Wa2[k] = s2 * LOG2E;
    }
    for (int idx = gt; idx < IN_F * OUT_F; idx += gridDim.x * blockDim.x) {
        int j    = idx & 7;
        int lane = (idx >> 3) & 63;
        int nb   = (idx >> 9) & 7;
        int kb   = idx >> 12;
        int k = kb * 32 + (lane >> 4) * 8 + j;
        int n = nb * 16 + (lane & 15);
        Wp[idx] = (_Float16)W[k * OUT_F + n];
    }
}

// ---------------------------------------------------------------------------
// Kernel 2: wh1[i] = node_emb[i] . Wa1 ; wh2[j] = attr_emb[j] . Wa2
// ---------------------------------------------------------------------------
__global__ __launch_bounds__(256) void wh_kernel(
    const float* __restrict__ node_emb, const float* __restrict__ attr_emb,
    const float* __restrict__ Wa1, const float* __restrict__ Wa2,
    float* __restrict__ wh1, float* __restrict__ wh2) {
    int wave = threadIdx.x >> 6, lane = threadIdx.x & 63;
    int r = blockIdx.x * 4 + wave;   // grid = 6250 -> r in [0, 25000)
    const float* src;
    const float* vec;
    float* dst;
    if (r < N_NODES) {
        src = node_emb + (size_t)r * IN_F; vec = Wa1; dst = wh1 + r;
    } else {
        int r2 = r - N_NODES;
        src = attr_emb + (size_t)r2 * IN_F; vec = Wa2; dst = wh2 + r2;
    }
    float4 ra = *reinterpret_cast<const float4*>(src + lane * 8);
    float4 rb = *reinterpret_cast<const float4*>(src + lane * 8 + 4);
    const float* vp = vec + lane * 8;
    float s = ra.x * vp[0] + ra.y * vp[1] + ra.z * vp[2] + ra.w * vp[3]
            + rb.x * vp[4] + rb.y * vp[5] + rb.z * vp[6] + rb.w * vp[7];
#pragma unroll
    for (int off = 1; off < 64; off <<= 1) s += __shfl_xor(s, off, 64);
    if (lane == 0) *dst = s;
}

// ---------------------------------------------------------------------------
// Kernel 2b: maxwh2 = max_j wh2[j]; fill wh2 pad with NEGBIG. single block.
// ---------------------------------------------------------------------------
__global__ __launch_bounds__(256) void max_kernel(
    float* __restrict__ wh2, float* __restrict__ maxp) {
    __shared__ float red[4];
    int t = threadIdx.x;
    float m = -1e30f;
    for (int j = t; j < N_ATTRS; j += 256) m = fmaxf(m, wh2[j]);
    for (int j = N_ATTRS + t; j < WH2_PAD; j += 256) wh2[j] = NEGBIG;
#pragma unroll
    for (int off = 1; off < 64; off <<= 1) m = fmaxf(m, __shfl_xor(m, off, 64));
    int wave = t >> 6, lane = t & 63;
    if (lane == 0) red[wave] = m;
    __syncthreads();
    if (t == 0) *maxp = fmaxf(fmaxf(red[0], red[1]), fmaxf(red[2], red[3]));
}

// ---------------------------------------------------------------------------
// Kernel 3: V = attr_emb @ W  [5120(pad) x 128] f16 in B-fragment order:
// Vp[kk*4096 + nb*512 + lane*8 + jj] = V[kk*32 + (lane>>4)*8 + jj][nb*16 + (lane&15)]
// grid 320 x 64: ONE wave per block -> spreads over all 256 CUs (the old
// 80x256 config parked 4 waves on each of only 80 CUs).
// ---------------------------------------------------------------------------
__global__ __launch_bounds__(64) void attr_h_kernel(
    const float* __restrict__ attr_emb, const _Float16* __restrict__ Wp,
    _Float16* __restrict__ Vp) {
    int lane = threadIdx.x & 63;
    int m = lane & 15, quad = lane >> 4;
    int j0 = blockIdx.x * 16;               // grid = 320 -> j0 in [0, 5120)
    int j = j0 + m;
    bool valid = j < N_ATTRS;
    f32x4 acc[8];
#pragma unroll
    for (int nb = 0; nb < 8; ++nb)
#pragma unroll
        for (int t = 0; t < 4; ++t) acc[nb][t] = 0.f;
    const float* arow = attr_emb + (size_t)j * IN_F;
    for (int kk = 0; kk < IN_F / 32; ++kk) {
        f16x8 afrag;
        if (valid) {
            float4 ra = *reinterpret_cast<const float4*>(arow + kk * 32 + quad * 8);
            float4 rb = *reinterpret_cast<const float4*>(arow + kk * 32 + quad * 8 + 4);
            afrag[0] = (_Float16)ra.x; afrag[1] = (_Float16)ra.y;
            afrag[2] = (_Float16)ra.z; afrag[3] = (_Float16)ra.w;
            afrag[4] = (_Float16)rb.x; afrag[5] = (_Float16)rb.y;
            afrag[6] = (_Float16)rb.z; afrag[7] = (_Float16)rb.w;
        } else {
#pragma unroll
            for (int t = 0; t < 8; ++t) afrag[t] = (_Float16)0.f;
        }
        const _Float16* wbase = Wp + (size_t)(kk * 8) * 64 * 8;
#pragma unroll
        for (int nb = 0; nb < 8; ++nb) {
            f16x8 bfrag;
            __builtin_memcpy(&bfrag, wbase + (nb * 64 + lane) * 8, 16);
            acc[nb] = __builtin_amdgcn_mfma_f32_16x16x32_f16(afrag, bfrag, acc[nb], 0, 0, 0);
        }
    }
#pragma unroll
    for (int nb = 0; nb < 8; ++nb) {
#pragma unroll
        for (int reg = 0; reg < 4; ++reg) {
            int jr = j0 + quad * 4 + reg;
            int n = nb * 16 + m;
            float v = (jr < N_ATTRS) ? acc[nb][reg] : 0.f;  // zero the K padding
            size_t idx = ((size_t)((jr >> 5) * 8 + nb) * 64 +
                          (((jr >> 3) & 3) * 16 + m)) * 8 + (jr & 7);
            Vp[idx] = (_Float16)v;
        }
    }
}

// ---------------------------------------------------------------------------
// Kernel 4 (main), barrier-enforced pipeline, Vp DIRECT FROM L2 (no staging):
//  - block = 32 rows (grid 625), 4 waves; wave w: row group (w>>1)*16,
//    kstep parity w&1. Superstep = 2 ksteps (64 attrs).
//  - Per superstep, async global_load_lds stages ONLY feat (8 KB, per-wave,
//    A-frag order -> conflict-free ds_read_b128) + wh2 (256 B) into a double
//    buffer; ONE barrier; compute reads feat/wh2 from LDS, Vp from global.
//  - Vp (1.31 MB) is L2-resident: staging it through LDS was pure overhead
//    (32 KB LDS + 16 KB/superstep extra vmcnt drain). Bfrag loads are issued
//    BEFORE the next superstep's feat DMA (sched_barrier pin) so the
//    in-order vmcnt retire of bfrags never waits on a fresh HBM feat load.
//  - LDS 16.9 KB -> __launch_bounds__(256,4): 4 blocks/CU, 16 waves/CU.
// ---------------------------------------------------------------------------
__global__ __launch_bounds__(256, 4) void attn_kernel(
    const int* __restrict__ feat, const float* __restrict__ wh1,
    const float* __restrict__ wh2, const float* __restrict__ maxwh2,
    const _Float16* __restrict__ Vp, float* __restrict__ out) {
    __shared__ __align__(16) char lds[16896];   // fbuf 2x8K | wbuf 2x256
    __shared__ float rsums[32];

    int wave = threadIdx.x >> 6, lane = threadIdx.x & 63;
    int m = lane & 15, quad = lane >> 4;
    int i0 = blockIdx.x * 32;
    int rg = (wave >> 1) * 16;         // row-group base (0 or 16)
    int half = wave & 1;               // kstep parity

    float wh1i = wh1[i0 + rg + m];     // scaled by log2(e)
    float emax = wh1i + maxwh2[0];
    float Mi = fmaxf(emax, 0.2f * emax) - 12.f;   // f16 P in (0, 4096]

    f32x4 acc[8];
#pragma unroll
    for (int nb = 0; nb < 8; ++nb)
#pragma unroll
        for (int t = 0; t < 4; ++t) acc[nb][t] = 0.f;
    float s = 0.f;

    char* fbuf0 = lds;                 // 8192 per buffer
    char* wbuf0 = lds + 16384;         // 256 per buffer

    const char* featb = (const char*)feat;
    size_t frow_off = (size_t)(i0 + rg + m) * N_ATTRS * 4;   // this lane's row

    // ---- staging for superstep ss into buffer b (async DMA, no waits) ----
    auto stage = [&](int ss, int b) {
        // feat: this wave's kstep, A-frag order (lane m=row, quad*8 attrs)
        int kbase = (2 * ss + half) * 32;
        char* fdst = fbuf0 + b * 8192 + wave * 2048;
#pragma unroll
        for (int h = 0; h < 2; ++h) {
            int a = kbase + quad * 8 + h * 4;
            a = min(a, N_ATTRS - 4);               // tail clamp (wh2 NEGBIG masks)
            async16(fdst + h * 1024, featb + frow_off + (size_t)a * 4);
        }
        // wh2: 64 floats for the superstep (wave 0, lanes 0-15)
        if (wave == 0 && lane < 16)
            async16(wbuf0 + b * 256, (const char*)(wh2 + ss * 64) + lane * 16);
    };

    stage(0, 0);
    __syncthreads();

    for (int ss = 0; ss < NSS; ++ss) {
        int cur = ss & 1;

        // (1) Vp bfrags: direct global loads (L2-resident), issued FIRST so
        //     their vmcnt retire is not blocked by the HBM feat DMA below.
        f16x8 bf[8];
        const _Float16* vb = Vp + (size_t)(2 * ss + half) * 4096 + lane * 8;
#pragma unroll
        for (int nb = 0; nb < 8; ++nb)
            bf[nb] = *reinterpret_cast<const f16x8*>(vb + nb * 512);
        __builtin_amdgcn_sched_barrier(0);

        // (2) stage next superstep: DMA flies across the compute phase
        if (ss + 1 < NSS) stage(ss + 1, cur ^ 1);

        // (3) compute phase: feat/wh2 from LDS, Vp from registers
        char* wb = wbuf0 + cur * 256 + half * 128 + quad * 32;
        float4 wva = *reinterpret_cast<const float4*>(wb);
        float4 wvb = *reinterpret_cast<const float4*>(wb + 16);
        char* fb = fbuf0 + cur * 8192 + wave * 2048 + lane * 16;
        i32x4 fA = *reinterpret_cast<const i32x4*>(fb);
        i32x4 fB = *reinterpret_cast<const i32x4*>(fb + 1024);

        int   fi[8] = {fA.x, fA.y, fA.z, fA.w, fB.x, fB.y, fB.z, fB.w};
        float wv[8] = {wva.x, wva.y, wva.z, wva.w, wvb.x, wvb.y, wvb.z, wvb.w};
        f16x8 afrag;
#pragma unroll
        for (int t = 0; t < 8; ++t) {
            float e = wh1i + wv[t];                // pad attrs: e ~ -1e30
            float l = fmaxf(e, 0.2f * e);
            float p = fast_exp2(l - Mi);           // pad: exp2(-huge) = 0
            p = (fi[t] > 0) ? p : 0.f;
            _Float16 ph = (_Float16)p;
            s += (float)ph;                        // sum quantized p
            afrag[t] = ph;
        }

#pragma unroll
        for (int nb = 0; nb < 8; ++nb)
            acc[nb] = __builtin_amdgcn_mfma_f32_16x16x32_f16(afrag, bf[nb], acc[nb], 0, 0, 0);

        __syncthreads();   // drains s+1 staging; protects buffer swap
    }

    // ---- row sums for this wave's ksteps (rows rg..rg+15) ----
    s += __shfl_xor(s, 16, 64);
    s += __shfl_xor(s, 32, 64);

    // ---- combine kstep-parity pairs; accs overlay on fbuf (16 KB) ----
    float* accp = (float*)lds;   // [group][16][128]
    if (half == 0) {
#pragma unroll
        for (int nb = 0; nb < 8; ++nb)
#pragma unroll
            for (int reg = 0; reg < 4; ++reg)
                accp[(rg + quad * 4 + reg) * 128 + nb * 16 + m] = acc[nb][reg];
        if (lane < 16) rsums[rg + lane] = s;
    }
    __syncthreads();
    if (half == 1) {
#pragma unroll
        for (int nb = 0; nb < 8; ++nb)
#pragma unroll
            for (int reg = 0; reg < 4; ++reg)
                accp[(rg + quad * 4 + reg) * 128 + nb * 16 + m] += acc[nb][reg];
        if (lane < 16) rsums[rg + lane] += s;
    }
    __syncthreads();

    // ---- normalize, ELU, store fp32 (32 x 128) ----
    for (int o = threadIdx.x; o < 32 * 128; o += 256) {
        int lr = o >> 7, n = o & 127;
        float v = accp[lr * 128 + n];
        float rs = rsums[lr];
        rs = (rs > 0.f) ? rs : 1.f;
        float h = v / rs;
        float ov = (h > 0.f) ? h : (fast_exp2(h * LOG2E) - 1.f);
        out[(size_t)(i0 + lr) * OUT_F + n] = ov;
    }
}

// ---------------------------------------------------------------------------
extern "C" void kernel_launch(void* const* d_in, const int* in_sizes, int n_in,
                              void* d_out, int out_size, void* d_ws, size_t ws_size,
                              hipStream_t stream) {
    const float* node_emb = (const float*)d_in[0];  // fp32 [20000,512]
    const float* attr_emb = (const float*)d_in[1];  // fp32 [5000,512]
    const int*   feat     = (const int*)d_in[2];    // int32 [20000,5000]
    const float* W        = (const float*)d_in[3];  // fp32 [512,128]
    const float* a        = (const float*)d_in[4];  // fp32 [256,1]
    float*       out      = (float*)d_out;          // fp32 [20000,128]

    char* ws = (char*)d_ws;
    float*    Wa1 = (float*)(ws + 0);          // 512 f32
    float*    Wa2 = (float*)(ws + 4096);       // 512 f32
    float*    wh1 = (float*)(ws + 8192);       // 20000 f32 (ends 88192)
    float*    wh2 = (float*)(ws + 90112);      // 5376 f32 incl. NEGBIG pad (ends 111616)
    float*    mx  = (float*)(ws + 111616);     // 1 f32
    _Float16* Wp  = (_Float16*)(ws + 131072);  // 65536 f16 (ends 262144)
    _Float16* Vp  = (_Float16*)(ws + 262144);  // 5120*128 f16 (ends 1572864)

    prep_kernel<<<64, 256, 0, stream>>>(W, a, Wa1, Wa2, Wp);
    wh_kernel<<<6250, 256, 0, stream>>>(node_emb, attr_emb, Wa1, Wa2, wh1, wh2);
    max_kernel<<<1, 256, 0, stream>>>(wh2, mx);
    attr_h_kernel<<<320, 64, 0, stream>>>(attr_emb, Wp, Vp);
    attn_kernel<<<625, 256, 0, stream>>>(feat, wh1, wh2, mx, Vp, out);
}